// Round 13
// baseline (211.284 us; speedup 1.0000x reference)
//
#include <hip/hip_runtime.h>

#define S_LEN 8192
#define D_KK  128
// 1/sqrt(128) * log2(e): softmax runs in the exp2 domain
#define SCALE2 (0.08838834764831845f * 1.44269504088896340f)

typedef __bf16 bf16x2 __attribute__((ext_vector_type(2)));
typedef __bf16 bf16x4 __attribute__((ext_vector_type(4)));
typedef __bf16 bf16x8 __attribute__((ext_vector_type(8)));
typedef float  f32x16 __attribute__((ext_vector_type(16)));
typedef _Float16 half_t;

// ---------------------------------------------------------------------------
// Pre-pass: pack K and V into FRAGMENT-ORDER bf16 layouts (unchanged).
//   Kf[t*8+s][lane*8+j] = K[t*32 + (lane&31)][s*16 + (lane>>5)*8 + j]
//   Vf[t*8+f][lane*8+j] = V[t*32 + 16*(f&1) + 8*(lane>>5) + j][32*(f>>1) + (lane&31)]
// ---------------------------------------------------------------------------
__global__ __launch_bounds__(256) void prep_kv_23450521436217(
    const float* __restrict__ K,
    const float* __restrict__ V,
    __bf16* __restrict__ Kf,
    __bf16* __restrict__ Vf)
{
    const int tid = threadIdx.x;
    const int t   = blockIdx.x;
    __shared__ __bf16 T[32][140];

    const float* ktile = K + (size_t)t * 32 * D_KK;
    const float* vtile = V + (size_t)t * 32 * D_KK;

    const int row = tid & 31;
    const int cp  = tid >> 5;
    #pragma unroll
    for (int i = 0; i < 2; ++i) {
        int c = cp * 2 + i;
        int s = c >> 1, hi = c & 1;
        const float* src = ktile + row * D_KK + c * 8;
        float4 a = *(const float4*)(src);
        float4 b = *(const float4*)(src + 4);
        bf16x8 o;
        o[0]=(__bf16)a.x; o[1]=(__bf16)a.y; o[2]=(__bf16)a.z; o[3]=(__bf16)a.w;
        o[4]=(__bf16)b.x; o[5]=(__bf16)b.y; o[6]=(__bf16)b.z; o[7]=(__bf16)b.w;
        *(bf16x8*)(Kf + (size_t)(t * 8 + s) * 512 + hi * 256 + row * 8) = o;
    }

    #pragma unroll
    for (int i = 0; i < 4; ++i) {
        int f4 = tid + i * 256;
        float4 v = ((const float4*)vtile)[f4];
        int r = f4 >> 5, cc = (f4 & 31) << 2;
        bf16x4 b;
        b[0]=(__bf16)v.x; b[1]=(__bf16)v.y; b[2]=(__bf16)v.z; b[3]=(__bf16)v.w;
        *(bf16x4*)(&T[r][cc]) = b;
    }
    __syncthreads();

    #pragma unroll
    for (int i = 0; i < 2; ++i) {
        int idx  = tid + i * 256;
        int frag = idx >> 6, lane = idx & 63;
        int hi = lane >> 5, l5 = lane & 31;
        int d = frag >> 1, h = frag & 1;
        bf16x8 o;
        #pragma unroll
        for (int j = 0; j < 8; ++j) o[j] = T[16 * h + 8 * hi + j][32 * d + l5];
        *(bf16x8*)(Vf + (size_t)(t * 8 + frag) * 512 + lane * 8) = o;
    }
}

// ---------------------------------------------------------------------------
// Phase A: PRODUCER/CONSUMER wave specialization.
// Occupancy model (fit of r5..r12): waves/SIMD = 512 / roundup64(VGPR+AGPR);
// binary in practice: total <=128 -> 4 waves/SIMD, else 2. Full per-wave
// state (qf+oacc+vb+c ~180) can't fit 128 -> split the PIPELINE across a
// wave pair instead of duplicating work (r10's mistake):
//   producer (wave 0..3):  QK^T (LDS K) + softmax + P-pack -> LDS (P, alpha)
//   consumer (wave 4..7):  V loads (TA path) + alpha-rescale + PV -> oacc
// Each path's registers are branch-local -> allocator overlays them; cap
// enforced by launch_bounds(512,4) (=128/wave) -> 2 blocks/CU co-resident.
// Consumer lags producer by 1 tile; ONE barrier per iteration.
// Grid = (S_LEN/128) q-tiles x NS kv-splits; pair p owns q-subtile qt*4+p.
// ---------------------------------------------------------------------------
template<int NS>
__global__ __launch_bounds__(512, 4) void attn_part_23450521436217(
    const float*  __restrict__ Q,
    const __bf16* __restrict__ Kf,
    const __bf16* __restrict__ Vf,
    half_t* __restrict__ P16,
    float*  __restrict__ Mp,
    float*  __restrict__ Lp)
{
    constexpr int ITERS = 256 / NS;    // 32-key tiles per split
    const int tid  = threadIdx.x;
    const int wave = tid >> 6;    // 0..7
    const int lane = tid & 63;
    const int l5   = lane & 31;
    const int hi   = lane >> 5;
    const int pair = wave & 3;    // q-subtile within block
    const bool producer = wave < 4;

    const int ks   = blockIdx.x & (NS - 1);   // kv split (XCD-aligned)
    const int qt   = blockIdx.x / NS;         // 128-row q-tile
    const int qsub = qt * 4 + pair;           // global 32-row q-subtile id
    const int qrow = qsub * 32 + l5;

    __shared__ __align__(16) __bf16 Klds[2][4096];        // 16 KB K dbuf
    __shared__ __align__(16) unsigned Pl[4][2][2][64][4]; // 16 KB P dbuf
    __shared__ float Al[4][2][32];                        // alpha dbuf

    const __bf16* kbase = Kf + (size_t)(ks * ITERS) * 4096;

    float m_run = -1e30f, l_run = 0.0f;      // producer state
    f32x16 oacc[4];                          // consumer state
    #pragma unroll
    for (int d = 0; d < 4; ++d) oacc[d] = f32x16{};

    bf16x8 qf[8];
    if (producer) {
        // Q fragments (B operand), SCALE2 folded in
        #pragma unroll
        for (int s = 0; s < 8; ++s) {
            const float* qp = Q + (size_t)qrow * D_KK + s * 16 + hi * 8;
            float4 a = *(const float4*)(qp);
            float4 b = *(const float4*)(qp + 4);
            bf16x8 f;
            f[0]=(__bf16)(a.x*SCALE2); f[1]=(__bf16)(a.y*SCALE2);
            f[2]=(__bf16)(a.z*SCALE2); f[3]=(__bf16)(a.w*SCALE2);
            f[4]=(__bf16)(b.x*SCALE2); f[5]=(__bf16)(b.y*SCALE2);
            f[6]=(__bf16)(b.z*SCALE2); f[7]=(__bf16)(b.w*SCALE2);
            qf[s] = f;
        }
        // stage K tile 0 (each producer stages 2 x 1KB fragment-blocks)
        #pragma unroll
        for (int s2 = 0; s2 < 2; ++s2) {
            const int frag = pair * 2 + s2;
            const __bf16* src = kbase + frag * 512 + lane * 8;
            __builtin_amdgcn_global_load_lds(
                (const __attribute__((address_space(1))) void*)src,
                (__attribute__((address_space(3))) void*)&Klds[0][frag * 512],
                16, 0, 0);
        }
    }
    __syncthreads();

    const __bf16* vfp = Vf + (size_t)(ks * ITERS) * 4096 + lane * 8;

    for (int t = 0; t < ITERS; ++t) {
        if (producer) {
            const int cur = t & 1;
            // stage K(t+1) into the other buffer
            if (t < ITERS - 1) {
                #pragma unroll
                for (int s2 = 0; s2 < 2; ++s2) {
                    const int frag = pair * 2 + s2;
                    const __bf16* src = kbase + (size_t)(t + 1) * 4096
                                      + frag * 512 + lane * 8;
                    __builtin_amdgcn_global_load_lds(
                        (const __attribute__((address_space(1))) void*)src,
                        (__attribute__((address_space(3))) void*)&Klds[cur ^ 1][frag * 512],
                        16, 0, 0);
                }
            }

            // QK^T swapped: S^T[key][q], key=(r&3)+8*(r>>2)+4*hi, q=l5
            f32x16 c = f32x16{};
            __builtin_amdgcn_s_setprio(1);
            #pragma unroll
            for (int s = 0; s < 8; ++s) {
                bf16x8 kf = *(const bf16x8*)(&Klds[cur][s * 512 + lane * 8]);
                c = __builtin_amdgcn_mfma_f32_32x32x16_bf16(kf, qf[s], c, 0, 0, 0);
            }
            __builtin_amdgcn_s_setprio(0);

            // online softmax (exp2 domain), defer-max THR=11.5
            float x0 = fmaxf(c[0], c[8]),  x1 = fmaxf(c[1], c[9]);
            float x2 = fmaxf(c[2], c[10]), x3 = fmaxf(c[3], c[11]);
            float x4 = fmaxf(c[4], c[12]), x5 = fmaxf(c[5], c[13]);
            float x6 = fmaxf(c[6], c[14]), x7 = fmaxf(c[7], c[15]);
            float y0 = fmaxf(fmaxf(x0, x4), fmaxf(x1, x5));
            float y1 = fmaxf(fmaxf(x2, x6), fmaxf(x3, x7));
            float tmax = fmaxf(y0, y1);
            tmax = fmaxf(tmax, __shfl_xor(tmax, 32));
            float alpha = 1.0f;
            if (__any(tmax > m_run + 11.5f)) {
                float mnew = fmaxf(m_run, tmax);
                alpha = exp2f(m_run - mnew);
                l_run *= alpha;
                m_run  = mnew;
            }
            float p[16];
            #pragma unroll
            for (int r = 0; r < 16; ++r) p[r] = exp2f(c[r] - m_run);
            float s0a = (p[0]+p[1]) + (p[2]+p[3]),   s1a = (p[4]+p[5]) + (p[6]+p[7]);
            float s2a = (p[8]+p[9]) + (p[10]+p[11]), s3a = (p[12]+p[13]) + (p[14]+p[15]);
            float ps = (s0a + s1a) + (s2a + s3a);
            ps += __shfl_xor(ps, 32);
            l_run += ps;

            // P -> bf16 packs; permlane32_swap -> PV B-operand words
            unsigned pk[8];
            #pragma unroll
            for (int tq = 0; tq < 8; ++tq) {
                bf16x2 w; w[0] = (__bf16)p[2*tq]; w[1] = (__bf16)p[2*tq+1];
                pk[tq] = __builtin_bit_cast(unsigned, w);
            }
            asm volatile("v_permlane32_swap_b32 %0, %1" : "+v"(pk[0]), "+v"(pk[2]));
            asm volatile("v_permlane32_swap_b32 %0, %1" : "+v"(pk[1]), "+v"(pk[3]));
            asm volatile("v_permlane32_swap_b32 %0, %1" : "+v"(pk[4]), "+v"(pk[6]));
            asm volatile("v_permlane32_swap_b32 %0, %1" : "+v"(pk[5]), "+v"(pk[7]));

            // publish P(t) + alpha(t)
            uint4 b0 = make_uint4(pk[0], pk[1], pk[2], pk[3]);
            uint4 b1 = make_uint4(pk[4], pk[5], pk[6], pk[7]);
            *(uint4*)&Pl[pair][cur][0][lane][0] = b0;
            *(uint4*)&Pl[pair][cur][1][lane][0] = b1;
            if (lane < 32) Al[pair][cur][lane] = alpha;
        } else if (t > 0) {
            const int b = (t - 1) & 1;
            // V fragments for tile t-1 (issue first: latency under P-read)
            const __bf16* vt = vfp + (size_t)(t - 1) * 4096;
            bf16x8 vb[8];
            #pragma unroll
            for (int f = 0; f < 8; ++f) vb[f] = *(const bf16x8*)(vt + f * 512);

            union { uint4 u; bf16x8 f; } pb0, pb1;
            pb0.u = *(const uint4*)&Pl[pair][b][0][lane][0];
            pb1.u = *(const uint4*)&Pl[pair][b][1][lane][0];
            float alpha = Al[pair][b][l5];
            if (__any(alpha != 1.0f)) {
                #pragma unroll
                for (int d = 0; d < 4; ++d) oacc[d] *= alpha;
            }
            __builtin_amdgcn_s_setprio(1);
            #pragma unroll
            for (int d = 0; d < 4; ++d) {
                oacc[d] = __builtin_amdgcn_mfma_f32_32x32x16_bf16(vb[2*d+0], pb0.f,
                                                                  oacc[d], 0,0,0);
                oacc[d] = __builtin_amdgcn_mfma_f32_32x32x16_bf16(vb[2*d+1], pb1.f,
                                                                  oacc[d], 0,0,0);
            }
            __builtin_amdgcn_s_setprio(0);
        }
        __syncthreads();
    }

    // ---- epilogue ----
    if (producer) {
        if (lane < 32) {
            Mp[ks * S_LEN + qrow] = m_run;
            Lp[ks * S_LEN + qrow] = l_run;
        }
    } else {
        // final PV for tile ITERS-1
        const int b = (ITERS - 1) & 1;
        const __bf16* vt = vfp + (size_t)(ITERS - 1) * 4096;
        bf16x8 vb[8];
        #pragma unroll
        for (int f = 0; f < 8; ++f) vb[f] = *(const bf16x8*)(vt + f * 512);
        union { uint4 u; bf16x8 f; } pb0, pb1;
        pb0.u = *(const uint4*)&Pl[pair][b][0][lane][0];
        pb1.u = *(const uint4*)&Pl[pair][b][1][lane][0];
        float alpha = Al[pair][b][l5];
        if (__any(alpha != 1.0f)) {
            #pragma unroll
            for (int d = 0; d < 4; ++d) oacc[d] *= alpha;
        }
        #pragma unroll
        for (int d = 0; d < 4; ++d) {
            oacc[d] = __builtin_amdgcn_mfma_f32_32x32x16_bf16(vb[2*d+0], pb0.f,
                                                              oacc[d], 0,0,0);
            oacc[d] = __builtin_amdgcn_mfma_f32_32x32x16_bf16(vb[2*d+1], pb1.f,
                                                              oacc[d], 0,0,0);
        }
        // write unnormalized partial O^T (fp16)
        half_t* pb = P16 + (size_t)(ks * 256 + qsub) * (128 * 32);
        #pragma unroll
        for (int d = 0; d < 4; ++d)
            #pragma unroll
            for (int reg = 0; reg < 16; ++reg) {
                int drow = d * 32 + (reg & 3) + 8 * (reg >> 2) + 4 * hi;
                pb[drow * 32 + l5] = (half_t)oacc[d][reg];
            }
    }
}

// ---------------------------------------------------------------------------
// Phase B (template over NS): merge NS kv-split partials per q-row.
// ---------------------------------------------------------------------------
template<int NS>
__global__ __launch_bounds__(256) void attn_merge_23450521436217(
    const half_t* __restrict__ P16,
    const float*  __restrict__ Mp,
    const float*  __restrict__ Lp,
    float* __restrict__ O)
{
    const int tid  = threadIdx.x;
    const int qsub = blockIdx.x;

    __shared__ float W[NS][32];
    __shared__ float Li[32];
    __shared__ float Ot[128][33];

    if (tid < 32) {
        const int qrow = qsub * 32 + tid;
        float m[NS], l[NS];
        #pragma unroll
        for (int ks = 0; ks < NS; ++ks) {
            m[ks] = Mp[ks * S_LEN + qrow];
            l[ks] = Lp[ks * S_LEN + qrow];
        }
        float M = m[0];
        #pragma unroll
        for (int ks = 1; ks < NS; ++ks) M = fmaxf(M, m[ks]);
        float L = 0.0f;
        #pragma unroll
        for (int ks = 0; ks < NS; ++ks) {
            float w = exp2f(m[ks] - M);
            W[ks][tid] = w;
            L += l[ks] * w;
        }
        Li[tid] = 1.0f / L;
    }
    __syncthreads();

    const int q  = tid & 31;
    const int dg = tid >> 5;          // 0..7
    #pragma unroll
    for (int j = 0; j < 16; ++j) {
        const int d = dg * 16 + j;
        float acc = 0.0f;
        #pragma unroll
        for (int ks = 0; ks < NS; ++ks)
            acc += W[ks][q] *
                   (float)P16[(size_t)(ks * 256 + qsub) * (128 * 32) + d * 32 + q];
        Ot[d][q] = acc;
    }
    __syncthreads();

    const int qq = tid >> 3;
    const int dv = (tid & 7) * 16;
    const float il = Li[qq];
    float* op = O + (size_t)(qsub * 32 + qq) * D_KK + dv;
    #pragma unroll
    for (int i = 0; i < 4; ++i) {
        float4 o;
        o.x = Ot[dv + i*4 + 0][qq] * il;
        o.y = Ot[dv + i*4 + 1][qq] * il;
        o.z = Ot[dv + i*4 + 2][qq] * il;
        o.w = Ot[dv + i*4 + 3][qq] * il;
        ((float4*)op)[i] = o;
    }
}

extern "C" void kernel_launch(void* const* d_in, const int* in_sizes, int n_in,
                              void* d_out, int out_size, void* d_ws, size_t ws_size,
                              hipStream_t stream) {
    const float* Q = (const float*)d_in[0];
    const float* K = (const float*)d_in[1];
    const float* V = (const float*)d_in[2];
    float* O = (float*)d_out;

    char* ws = (char*)d_ws;
    const size_t kf_b = (size_t)S_LEN * D_KK * 2;        // 2 MB
    __bf16* Kf = (__bf16*)(ws);
    __bf16* Vf = (__bf16*)(ws + kf_b);

    hipLaunchKernelGGL(prep_kv_23450521436217, dim3(S_LEN/32), dim3(256), 0, stream,
                       K, V, Kf, Vf);

    // NS=16 needs 2*kf_b + 2*16*S_LEN*4 + 16*256*4096*2 = ~38 MB of ws.
    const size_t need16 = 2 * kf_b + (size_t)2 * 16 * S_LEN * 4
                        + (size_t)16 * 256 * 4096 * 2;
    if (ws_size >= need16) {
        float*  Mp = (float*) (ws + 2 * kf_b);                      // 512 KB
        float*  Lp = (float*) (ws + 2 * kf_b + 16 * S_LEN * 4);     // 512 KB
        half_t* P16= (half_t*)(ws + 2 * kf_b + 32 * S_LEN * 4);     // 33.5 MB
        hipLaunchKernelGGL((attn_part_23450521436217<16>), dim3(64 * 16), dim3(512),
                           0, stream, Q, Kf, Vf, P16, Mp, Lp);
        hipLaunchKernelGGL((attn_merge_23450521436217<16>), dim3(S_LEN/32), dim3(256),
                           0, stream, P16, Mp, Lp, O);
    } else {
        float*  Mp = (float*) (ws + 2 * kf_b);                      // 256 KB
        float*  Lp = (float*) (ws + 2 * kf_b + 8 * S_LEN * 4);      // 256 KB
        half_t* P16= (half_t*)(ws + 2 * kf_b + 16 * S_LEN * 4);     // 16.8 MB
        hipLaunchKernelGGL((attn_part_23450521436217<8>), dim3(64 * 8), dim3(512),
                           0, stream, Q, Kf, Vf, P16, Mp, Lp);
        hipLaunchKernelGGL((attn_merge_23450521436217<8>), dim3(S_LEN/32), dim3(256),
                           0, stream, P16, Mp, Lp, O);
    }
}

// Round 15
// 73.030 us; speedup vs baseline: 2.8931x; 2.8931x over previous
//
#include <hip/hip_runtime.h>

#define S_LEN 8192
#define D_KK  128
// 1/sqrt(128) * log2(e): softmax runs in the exp2 domain
#define SCALE2 (0.08838834764831845f * 1.44269504088896340f)

typedef __bf16 bf16x2 __attribute__((ext_vector_type(2)));
typedef __bf16 bf16x4 __attribute__((ext_vector_type(4)));
typedef __bf16 bf16x8 __attribute__((ext_vector_type(8)));
typedef float  f32x16 __attribute__((ext_vector_type(16)));
typedef _Float16 half_t;

// ---------------------------------------------------------------------------
// Pre-pass: pack K and V into FRAGMENT-ORDER bf16 layouts (unchanged).
//   Kf[t*8+s][lane*8+j] = K[t*32 + (lane&31)][s*16 + (lane>>5)*8 + j]
//   Vf[t*8+f][lane*8+j] = V[t*32 + 16*(f&1) + 8*(lane>>5) + j][32*(f>>1) + (lane&31)]
// ---------------------------------------------------------------------------
__global__ __launch_bounds__(256) void prep_kv_23450521436217(
    const float* __restrict__ K,
    const float* __restrict__ V,
    __bf16* __restrict__ Kf,
    __bf16* __restrict__ Vf)
{
    const int tid = threadIdx.x;
    const int t   = blockIdx.x;
    __shared__ __bf16 T[32][140];

    const float* ktile = K + (size_t)t * 32 * D_KK;
    const float* vtile = V + (size_t)t * 32 * D_KK;

    const int row = tid & 31;
    const int cp  = tid >> 5;
    #pragma unroll
    for (int i = 0; i < 2; ++i) {
        int c = cp * 2 + i;
        int s = c >> 1, hi = c & 1;
        const float* src = ktile + row * D_KK + c * 8;
        float4 a = *(const float4*)(src);
        float4 b = *(const float4*)(src + 4);
        bf16x8 o;
        o[0]=(__bf16)a.x; o[1]=(__bf16)a.y; o[2]=(__bf16)a.z; o[3]=(__bf16)a.w;
        o[4]=(__bf16)b.x; o[5]=(__bf16)b.y; o[6]=(__bf16)b.z; o[7]=(__bf16)b.w;
        *(bf16x8*)(Kf + (size_t)(t * 8 + s) * 512 + hi * 256 + row * 8) = o;
    }

    #pragma unroll
    for (int i = 0; i < 4; ++i) {
        int f4 = tid + i * 256;
        float4 v = ((const float4*)vtile)[f4];
        int r = f4 >> 5, cc = (f4 & 31) << 2;
        bf16x4 b;
        b[0]=(__bf16)v.x; b[1]=(__bf16)v.y; b[2]=(__bf16)v.z; b[3]=(__bf16)v.w;
        *(bf16x4*)(&T[r][cc]) = b;
    }
    __syncthreads();

    #pragma unroll
    for (int i = 0; i < 2; ++i) {
        int idx  = tid + i * 256;
        int frag = idx >> 6, lane = idx & 63;
        int hi = lane >> 5, l5 = lane & 31;
        int d = frag >> 1, h = frag & 1;
        bf16x8 o;
        #pragma unroll
        for (int j = 0; j < 8; ++j) o[j] = T[16 * h + 8 * hi + j][32 * d + l5];
        *(bf16x8*)(Vf + (size_t)(t * 8 + frag) * 512 + lane * 8) = o;
    }
}

// ---------------------------------------------------------------------------
// Phase A: partial flash attention — r8 structure (proven correct, 2 waves/
// SIMD), with BOTH K and V staged through double-buffered LDS.
// Rationale: at 2 waves/SIMD the wall is per-CU L2 delivery. r8 shared K via
// LDS (8KB/block-iter) but V stayed wave-private (8 waves x 8KB = 64KB/
// block-iter). Sharing V too cuts global traffic per block-iter 72->16KB;
// LDS read load (128KB/block-iter at ~112B/cyc) now balances MFMA/VALU.
// Grid = 32 q-tiles x 8 kv-splits (ks = bid&7, XCD-aligned). Block = 512
// thr (8 waves), wave = q-subtile. One barrier per iteration; each wave
// stages 1KB of K and 1KB of V for tile it+1 via global_load_lds.
// Softmax in exp2 domain, defer-max THR=11.5.
// ---------------------------------------------------------------------------
__global__ __launch_bounds__(512, 2) void attn_part_23450521436217(
    const float*  __restrict__ Q,
    const __bf16* __restrict__ Kf,
    const __bf16* __restrict__ Vf,
    half_t* __restrict__ P16,
    float*  __restrict__ Mp,
    float*  __restrict__ Lp)
{
    const int tid  = threadIdx.x;
    const int wave = tid >> 6;    // 0..7 -> q-subtile
    const int lane = tid & 63;
    const int l5   = lane & 31;   // q column (B ops) / A row (K,V ops)
    const int hi   = lane >> 5;   // k-half within MFMA

    const int ks   = blockIdx.x & 7;   // kv split (XCD-aligned)
    const int qt   = blockIdx.x >> 3;  // q-tile 0..31
    const int qsub = qt * 8 + wave;    // global 32-row q-subtile id
    const int qrow = qsub * 32 + l5;

    __shared__ __align__(16) __bf16 Klds[2][4096];   // 16 KB K dbuf
    __shared__ __align__(16) __bf16 Vlds[2][4096];   // 16 KB V dbuf

    // Q fragments (B operand), SCALE2 folded in (exp2-domain softmax)
    bf16x8 qf[8];
    #pragma unroll
    for (int s = 0; s < 8; ++s) {
        const float* qp = Q + (size_t)qrow * D_KK + s * 16 + hi * 8;
        float4 a = *(const float4*)(qp);
        float4 b = *(const float4*)(qp + 4);
        bf16x8 f;
        f[0]=(__bf16)(a.x*SCALE2); f[1]=(__bf16)(a.y*SCALE2);
        f[2]=(__bf16)(a.z*SCALE2); f[3]=(__bf16)(a.w*SCALE2);
        f[4]=(__bf16)(b.x*SCALE2); f[5]=(__bf16)(b.y*SCALE2);
        f[6]=(__bf16)(b.z*SCALE2); f[7]=(__bf16)(b.w*SCALE2);
        qf[s] = f;
    }

    f32x16 oacc[4];
    #pragma unroll
    for (int d = 0; d < 4; ++d) oacc[d] = f32x16{};
    float m_run = -1e30f, l_run = 0.0f;

    const __bf16* kbase = Kf + (size_t)(ks * 32) * 4096;   // 32 tiles
    const __bf16* vbase = Vf + (size_t)(ks * 32) * 4096;

    // prologue: stage K0 + V0 (each wave: 1KB of K, 1KB of V)
    {
        const __bf16* ksrc = kbase + wave * 512 + lane * 8;
        __builtin_amdgcn_global_load_lds(
            (const __attribute__((address_space(1))) void*)ksrc,
            (__attribute__((address_space(3))) void*)&Klds[0][wave * 512],
            16, 0, 0);
        const __bf16* vsrc = vbase + wave * 512 + lane * 8;
        __builtin_amdgcn_global_load_lds(
            (const __attribute__((address_space(1))) void*)vsrc,
            (__attribute__((address_space(3))) void*)&Vlds[0][wave * 512],
            16, 0, 0);
    }
    __syncthreads();

    for (int it = 0; it < 32; ++it) {
        const int cur = it & 1;

        // stage K(it+1) + V(it+1) into the other buffers
        if (it < 31) {
            const __bf16* ksrc = kbase + (size_t)(it + 1) * 4096 + wave * 512 + lane * 8;
            __builtin_amdgcn_global_load_lds(
                (const __attribute__((address_space(1))) void*)ksrc,
                (__attribute__((address_space(3))) void*)&Klds[cur ^ 1][wave * 512],
                16, 0, 0);
            const __bf16* vsrc = vbase + (size_t)(it + 1) * 4096 + wave * 512 + lane * 8;
            __builtin_amdgcn_global_load_lds(
                (const __attribute__((address_space(1))) void*)vsrc,
                (__attribute__((address_space(3))) void*)&Vlds[cur ^ 1][wave * 512],
                16, 0, 0);
        }

        // QK^T swapped from LDS: S^T[key][q], key=(r&3)+8*(r>>2)+4*hi, q=l5
        f32x16 c = f32x16{};
        __builtin_amdgcn_s_setprio(1);
        #pragma unroll
        for (int s = 0; s < 8; ++s) {
            bf16x8 kf = *(const bf16x8*)(&Klds[cur][s * 512 + lane * 8]);
            c = __builtin_amdgcn_mfma_f32_32x32x16_bf16(kf, qf[s], c, 0, 0, 0);
        }
        __builtin_amdgcn_s_setprio(0);

        // online softmax (exp2 domain): pairwise max tree, defer-max THR=11.5
        float x0 = fmaxf(c[0], c[8]),  x1 = fmaxf(c[1], c[9]);
        float x2 = fmaxf(c[2], c[10]), x3 = fmaxf(c[3], c[11]);
        float x4 = fmaxf(c[4], c[12]), x5 = fmaxf(c[5], c[13]);
        float x6 = fmaxf(c[6], c[14]), x7 = fmaxf(c[7], c[15]);
        float y0 = fmaxf(fmaxf(x0, x4), fmaxf(x1, x5));
        float y1 = fmaxf(fmaxf(x2, x6), fmaxf(x3, x7));
        float tmax = fmaxf(y0, y1);
        tmax = fmaxf(tmax, __shfl_xor(tmax, 32));
        if (__any(tmax > m_run + 11.5f)) {
            float mnew  = fmaxf(m_run, tmax);
            float alpha = exp2f(m_run - mnew);
            #pragma unroll
            for (int d = 0; d < 4; ++d) oacc[d] *= alpha;
            l_run *= alpha;
            m_run  = mnew;
        }
        float p[16];
        #pragma unroll
        for (int r = 0; r < 16; ++r) p[r] = exp2f(c[r] - m_run);
        float s0a = (p[0]+p[1]) + (p[2]+p[3]),   s1a = (p[4]+p[5]) + (p[6]+p[7]);
        float s2a = (p[8]+p[9]) + (p[10]+p[11]), s3a = (p[12]+p[13]) + (p[14]+p[15]);
        float ps = (s0a + s1a) + (s2a + s3a);
        ps += __shfl_xor(ps, 32);
        l_run += ps;

        // P -> bf16 packs; permlane32_swap -> PV B-operand words
        unsigned pk[8];
        #pragma unroll
        for (int tq = 0; tq < 8; ++tq) {
            bf16x2 w; w[0] = (__bf16)p[2*tq]; w[1] = (__bf16)p[2*tq+1];
            pk[tq] = __builtin_bit_cast(unsigned, w);
        }
        asm volatile("v_permlane32_swap_b32 %0, %1" : "+v"(pk[0]), "+v"(pk[2]));
        asm volatile("v_permlane32_swap_b32 %0, %1" : "+v"(pk[1]), "+v"(pk[3]));
        asm volatile("v_permlane32_swap_b32 %0, %1" : "+v"(pk[4]), "+v"(pk[6]));
        asm volatile("v_permlane32_swap_b32 %0, %1" : "+v"(pk[5]), "+v"(pk[7]));
        union { unsigned u[4]; bf16x8 f; } b0, b1;
        b0.u[0]=pk[0]; b0.u[1]=pk[1]; b0.u[2]=pk[2]; b0.u[3]=pk[3];
        b1.u[0]=pk[4]; b1.u[1]=pk[5]; b1.u[2]=pk[6]; b1.u[3]=pk[7];

        // PV: O^T[d][q] += V^T * P^T, V fragments from LDS
        __builtin_amdgcn_s_setprio(1);
        #pragma unroll
        for (int d = 0; d < 4; ++d) {
            bf16x8 v0 = *(const bf16x8*)(&Vlds[cur][(2*d)     * 512 + lane * 8]);
            bf16x8 v1 = *(const bf16x8*)(&Vlds[cur][(2*d + 1) * 512 + lane * 8]);
            oacc[d] = __builtin_amdgcn_mfma_f32_32x32x16_bf16(v0, b0.f,
                                                              oacc[d], 0,0,0);
            oacc[d] = __builtin_amdgcn_mfma_f32_32x32x16_bf16(v1, b1.f,
                                                              oacc[d], 0,0,0);
        }
        __builtin_amdgcn_s_setprio(0);

        __syncthreads();   // next tiles staged + all waves done with buf[cur]
    }

    // ---- write partials ----
    if (lane < 32) {
        Mp[ks * S_LEN + qrow] = m_run;
        Lp[ks * S_LEN + qrow] = l_run;
    }
    half_t* pb = P16 + (size_t)(ks * 256 + qsub) * (128 * 32);
    #pragma unroll
    for (int d = 0; d < 4; ++d)
        #pragma unroll
        for (int reg = 0; reg < 16; ++reg) {
            int drow = d * 32 + (reg & 3) + 8 * (reg >> 2) + 4 * hi;
            pb[drow * 32 + l5] = (half_t)oacc[d][reg];
        }
}

// ---------------------------------------------------------------------------
// Phase B: merge 8 kv-split partials per q-row (m in exp2 domain).
// ---------------------------------------------------------------------------
__global__ __launch_bounds__(256) void attn_merge_23450521436217(
    const half_t* __restrict__ P16,
    const float*  __restrict__ Mp,
    const float*  __restrict__ Lp,
    float* __restrict__ O)
{
    const int tid  = threadIdx.x;
    const int qsub = blockIdx.x;

    __shared__ float W[8][32];
    __shared__ float Li[32];
    __shared__ float Ot[128][33];

    if (tid < 32) {
        const int qrow = qsub * 32 + tid;
        float m[8], l[8];
        #pragma unroll
        for (int ks = 0; ks < 8; ++ks) {
            m[ks] = Mp[ks * S_LEN + qrow];
            l[ks] = Lp[ks * S_LEN + qrow];
        }
        float M = m[0];
        #pragma unroll
        for (int ks = 1; ks < 8; ++ks) M = fmaxf(M, m[ks]);
        float L = 0.0f;
        #pragma unroll
        for (int ks = 0; ks < 8; ++ks) {
            float w = exp2f(m[ks] - M);
            W[ks][tid] = w;
            L += l[ks] * w;
        }
        Li[tid] = 1.0f / L;
    }
    __syncthreads();

    const int q  = tid & 31;
    const int dg = tid >> 5;          // 0..7
    #pragma unroll
    for (int j = 0; j < 16; ++j) {
        const int d = dg * 16 + j;
        float acc = 0.0f;
        #pragma unroll
        for (int ks = 0; ks < 8; ++ks)
            acc += W[ks][q] *
                   (float)P16[(size_t)(ks * 256 + qsub) * (128 * 32) + d * 32 + q];
        Ot[d][q] = acc;
    }
    __syncthreads();

    const int qq = tid >> 3;
    const int dv = (tid & 7) * 16;
    const float il = Li[qq];
    float* op = O + (size_t)(qsub * 32 + qq) * D_KK + dv;
    #pragma unroll
    for (int i = 0; i < 4; ++i) {
        float4 o;
        o.x = Ot[dv + i*4 + 0][qq] * il;
        o.y = Ot[dv + i*4 + 1][qq] * il;
        o.z = Ot[dv + i*4 + 2][qq] * il;
        o.w = Ot[dv + i*4 + 3][qq] * il;
        ((float4*)op)[i] = o;
    }
}

extern "C" void kernel_launch(void* const* d_in, const int* in_sizes, int n_in,
                              void* d_out, int out_size, void* d_ws, size_t ws_size,
                              hipStream_t stream) {
    const float* Q = (const float*)d_in[0];
    const float* K = (const float*)d_in[1];
    const float* V = (const float*)d_in[2];
    float* O = (float*)d_out;

    char* ws = (char*)d_ws;
    const size_t kf_b = (size_t)S_LEN * D_KK * 2;        // 2 MB
    __bf16* Kf = (__bf16*)(ws);
    __bf16* Vf = (__bf16*)(ws + kf_b);
    float*  Mp = (float*) (ws + 2 * kf_b);               // 256 KB
    float*  Lp = (float*) (ws + 2 * kf_b + 8 * S_LEN * 4);
    half_t* P16= (half_t*)(ws + 2 * kf_b + 16 * S_LEN * 4);  // 16.8 MB

    hipLaunchKernelGGL(prep_kv_23450521436217, dim3(S_LEN/32), dim3(256), 0, stream,
                       K, V, Kf, Vf);
    hipLaunchKernelGGL(attn_part_23450521436217, dim3(256), dim3(512), 0, stream,
                       Q, Kf, Vf, P16, Mp, Lp);
    hipLaunchKernelGGL(attn_merge_23450521436217, dim3(S_LEN/32), dim3(256), 0, stream,
                       P16, Mp, Lp, O);
}

// Round 16
// 66.961 us; speedup vs baseline: 3.1553x; 1.0906x over previous
//
#include <hip/hip_runtime.h>

#define S_LEN 8192
#define D_KK  128
// 1/sqrt(128) * log2(e): softmax runs in the exp2 domain
#define SCALE2 (0.08838834764831845f * 1.44269504088896340f)

typedef __bf16 bf16x2 __attribute__((ext_vector_type(2)));
typedef __bf16 bf16x4 __attribute__((ext_vector_type(4)));
typedef __bf16 bf16x8 __attribute__((ext_vector_type(8)));
typedef float  f32x16 __attribute__((ext_vector_type(16)));
typedef _Float16 half_t;

// ---------------------------------------------------------------------------
// Pre-pass: pack K and V into FRAGMENT-ORDER bf16 layouts (unchanged).
//   Kf[t*8+s][lane*8+j] = K[t*32 + (lane&31)][s*16 + (lane>>5)*8 + j]
//   Vf[t*8+f][lane*8+j] = V[t*32 + 16*(f&1) + 8*(lane>>5) + j][32*(f>>1) + (lane&31)]
// ---------------------------------------------------------------------------
__global__ __launch_bounds__(256) void prep_kv_23450521436217(
    const float* __restrict__ K,
    const float* __restrict__ V,
    __bf16* __restrict__ Kf,
    __bf16* __restrict__ Vf)
{
    const int tid = threadIdx.x;
    const int t   = blockIdx.x;
    __shared__ __bf16 T[32][140];

    const float* ktile = K + (size_t)t * 32 * D_KK;
    const float* vtile = V + (size_t)t * 32 * D_KK;

    const int row = tid & 31;
    const int cp  = tid >> 5;
    #pragma unroll
    for (int i = 0; i < 2; ++i) {
        int c = cp * 2 + i;
        int s = c >> 1, hi = c & 1;
        const float* src = ktile + row * D_KK + c * 8;
        float4 a = *(const float4*)(src);
        float4 b = *(const float4*)(src + 4);
        bf16x8 o;
        o[0]=(__bf16)a.x; o[1]=(__bf16)a.y; o[2]=(__bf16)a.z; o[3]=(__bf16)a.w;
        o[4]=(__bf16)b.x; o[5]=(__bf16)b.y; o[6]=(__bf16)b.z; o[7]=(__bf16)b.w;
        *(bf16x8*)(Kf + (size_t)(t * 8 + s) * 512 + hi * 256 + row * 8) = o;
    }

    #pragma unroll
    for (int i = 0; i < 4; ++i) {
        int f4 = tid + i * 256;
        float4 v = ((const float4*)vtile)[f4];
        int r = f4 >> 5, cc = (f4 & 31) << 2;
        bf16x4 b;
        b[0]=(__bf16)v.x; b[1]=(__bf16)v.y; b[2]=(__bf16)v.z; b[3]=(__bf16)v.w;
        *(bf16x4*)(&T[r][cc]) = b;
    }
    __syncthreads();

    #pragma unroll
    for (int i = 0; i < 2; ++i) {
        int idx  = tid + i * 256;
        int frag = idx >> 6, lane = idx & 63;
        int hi = lane >> 5, l5 = lane & 31;
        int d = frag >> 1, h = frag & 1;
        bf16x8 o;
        #pragma unroll
        for (int j = 0; j < 8; ++j) o[j] = T[16 * h + 8 * hi + j][32 * d + l5];
        *(bf16x8*)(Vf + (size_t)(t * 8 + frag) * 512 + lane * 8) = o;
    }
}

// ---------------------------------------------------------------------------
// Phase A: r8 structure (K in LDS dbuf, V on TA path) with 64 KEYS PER
// BARRIER INTERVAL. Measured across r5/r7/r8/r15: pipe work ~3030 cyc/iter
// vs 4140 observed -> ~1100 cyc/iter of per-barrier fixed cost (drain +
// arrival skew). Processing two 32-key sub-tiles per __syncthreads halves
// the barrier count; vbB issued before PV-A so its latency hides under the
// MFMA stream. Registers: vbB loaded late -> peak ~100 VGPR + 64 AGPR
// (2 waves/SIMD, no spill). LDS = 2 buf x 2 sub-tiles x 8KB = 32 KB.
// Grid = 32 q-tiles x 8 kv-splits; block = 512 thr; wave = 32-row q-subtile.
// Softmax exp2-domain, defer-max THR=11.5. Partials (m, l, O^T fp16) -> ws.
// ---------------------------------------------------------------------------
__global__ __launch_bounds__(512, 2) void attn_part_23450521436217(
    const float*  __restrict__ Q,
    const __bf16* __restrict__ Kf,
    const __bf16* __restrict__ Vf,
    half_t* __restrict__ P16,
    float*  __restrict__ Mp,
    float*  __restrict__ Lp)
{
    const int tid  = threadIdx.x;
    const int wave = tid >> 6;    // 0..7 -> q-subtile
    const int lane = tid & 63;
    const int l5   = lane & 31;   // q column (B ops) / A row (K,V ops)
    const int hi   = lane >> 5;   // k-half within MFMA

    const int ks   = blockIdx.x & 7;   // kv split (XCD-aligned)
    const int qt   = blockIdx.x >> 3;  // q-tile 0..31
    const int qsub = qt * 8 + wave;    // global 32-row q-subtile id
    const int qrow = qsub * 32 + l5;

    __shared__ __align__(16) __bf16 Klds[2][2][4096];   // [buf][subtile], 32 KB

    // Q fragments (B operand), SCALE2 folded in (exp2-domain softmax)
    bf16x8 qf[8];
    #pragma unroll
    for (int s = 0; s < 8; ++s) {
        const float* qp = Q + (size_t)qrow * D_KK + s * 16 + hi * 8;
        float4 a = *(const float4*)(qp);
        float4 b = *(const float4*)(qp + 4);
        bf16x8 f;
        f[0]=(__bf16)(a.x*SCALE2); f[1]=(__bf16)(a.y*SCALE2);
        f[2]=(__bf16)(a.z*SCALE2); f[3]=(__bf16)(a.w*SCALE2);
        f[4]=(__bf16)(b.x*SCALE2); f[5]=(__bf16)(b.y*SCALE2);
        f[6]=(__bf16)(b.z*SCALE2); f[7]=(__bf16)(b.w*SCALE2);
        qf[s] = f;
    }

    f32x16 oacc[4];
    #pragma unroll
    for (int d = 0; d < 4; ++d) oacc[d] = f32x16{};
    float m_run = -1e30f, l_run = 0.0f;

    const __bf16* kbase = Kf + (size_t)(ks * 32) * 4096;   // 32 tiles
    const __bf16* vfp   = Vf + (size_t)(ks * 32) * 4096 + lane * 8;

    // prologue: stage K tiles 0,1 into buf 0 (each wave: 2 x 1KB)
    #pragma unroll
    for (int st = 0; st < 2; ++st) {
        const __bf16* src = kbase + (size_t)st * 4096 + wave * 512 + lane * 8;
        __builtin_amdgcn_global_load_lds(
            (const __attribute__((address_space(1))) void*)src,
            (__attribute__((address_space(3))) void*)&Klds[0][st][wave * 512],
            16, 0, 0);
    }
    __syncthreads();

// One 32-key sub-tile: QK from Klds[CUR][ST], softmax, pack, PV with V from
// the TA path at tile (2*IT+ST). VB must already hold the 8 V fragments.
#define SUBTILE(CUR, ST, IT, VB)                                               \
    {                                                                          \
        f32x16 c = f32x16{};                                                   \
        __builtin_amdgcn_s_setprio(1);                                         \
        _Pragma("unroll")                                                      \
        for (int s = 0; s < 8; ++s) {                                          \
            bf16x8 kf = *(const bf16x8*)(&Klds[CUR][ST][s * 512 + lane * 8]);  \
            c = __builtin_amdgcn_mfma_f32_32x32x16_bf16(kf, qf[s], c, 0, 0, 0);\
        }                                                                      \
        __builtin_amdgcn_s_setprio(0);                                         \
        float x0 = fmaxf(c[0], c[8]),  x1 = fmaxf(c[1], c[9]);                 \
        float x2 = fmaxf(c[2], c[10]), x3 = fmaxf(c[3], c[11]);                \
        float x4 = fmaxf(c[4], c[12]), x5 = fmaxf(c[5], c[13]);                \
        float x6 = fmaxf(c[6], c[14]), x7 = fmaxf(c[7], c[15]);                \
        float y0 = fmaxf(fmaxf(x0, x4), fmaxf(x1, x5));                        \
        float y1 = fmaxf(fmaxf(x2, x6), fmaxf(x3, x7));                        \
        float tmax = fmaxf(y0, y1);                                            \
        tmax = fmaxf(tmax, __shfl_xor(tmax, 32));                              \
        if (__any(tmax > m_run + 11.5f)) {                                     \
            float mnew  = fmaxf(m_run, tmax);                                  \
            float alpha = exp2f(m_run - mnew);                                 \
            _Pragma("unroll")                                                  \
            for (int d = 0; d < 4; ++d) oacc[d] *= alpha;                      \
            l_run *= alpha;                                                    \
            m_run  = mnew;                                                     \
        }                                                                      \
        float p[16];                                                           \
        _Pragma("unroll")                                                      \
        for (int r = 0; r < 16; ++r) p[r] = exp2f(c[r] - m_run);               \
        float s0a = (p[0]+p[1]) + (p[2]+p[3]),   s1a = (p[4]+p[5]) + (p[6]+p[7]);   \
        float s2a = (p[8]+p[9]) + (p[10]+p[11]), s3a = (p[12]+p[13]) + (p[14]+p[15]); \
        float ps = (s0a + s1a) + (s2a + s3a);                                  \
        ps += __shfl_xor(ps, 32);                                              \
        l_run += ps;                                                           \
        unsigned pk[8];                                                        \
        _Pragma("unroll")                                                      \
        for (int tq = 0; tq < 8; ++tq) {                                       \
            bf16x2 w; w[0] = (__bf16)p[2*tq]; w[1] = (__bf16)p[2*tq+1];        \
            pk[tq] = __builtin_bit_cast(unsigned, w);                          \
        }                                                                      \
        asm volatile("v_permlane32_swap_b32 %0, %1" : "+v"(pk[0]), "+v"(pk[2]));\
        asm volatile("v_permlane32_swap_b32 %0, %1" : "+v"(pk[1]), "+v"(pk[3]));\
        asm volatile("v_permlane32_swap_b32 %0, %1" : "+v"(pk[4]), "+v"(pk[6]));\
        asm volatile("v_permlane32_swap_b32 %0, %1" : "+v"(pk[5]), "+v"(pk[7]));\
        union { unsigned u[4]; bf16x8 f; } b0, b1;                             \
        b0.u[0]=pk[0]; b0.u[1]=pk[1]; b0.u[2]=pk[2]; b0.u[3]=pk[3];            \
        b1.u[0]=pk[4]; b1.u[1]=pk[5]; b1.u[2]=pk[6]; b1.u[3]=pk[7];            \
        __builtin_amdgcn_s_setprio(1);                                         \
        _Pragma("unroll")                                                      \
        for (int d = 0; d < 4; ++d) {                                          \
            oacc[d] = __builtin_amdgcn_mfma_f32_32x32x16_bf16(VB[2*d+0], b0.f, \
                                                              oacc[d], 0,0,0); \
            oacc[d] = __builtin_amdgcn_mfma_f32_32x32x16_bf16(VB[2*d+1], b1.f, \
                                                              oacc[d], 0,0,0); \
        }                                                                      \
        __builtin_amdgcn_s_setprio(0);                                         \
    }

    for (int it = 0; it < 16; ++it) {
        const int cur = it & 1;

        // stage K tiles 2it+2, 2it+3 into the other buffer
        if (it < 15) {
            #pragma unroll
            for (int st = 0; st < 2; ++st) {
                const __bf16* src = kbase + (size_t)(2*it + 2 + st) * 4096
                                  + wave * 512 + lane * 8;
                __builtin_amdgcn_global_load_lds(
                    (const __attribute__((address_space(1))) void*)src,
                    (__attribute__((address_space(3))) void*)&Klds[cur ^ 1][st][wave * 512],
                    16, 0, 0);
            }
        }

        // V fragments for sub-tile A (tile 2it)
        bf16x8 vbA[8];
        {
            const __bf16* vt = vfp + (size_t)(2*it) * 4096;
            #pragma unroll
            for (int f = 0; f < 8; ++f) vbA[f] = *(const bf16x8*)(vt + f * 512);
        }

        SUBTILE(cur, 0, it, vbA)

        // V fragments for sub-tile B (tile 2it+1) — latency under PV-A/QK-B
        bf16x8 vbB[8];
        {
            const __bf16* vt = vfp + (size_t)(2*it + 1) * 4096;
            #pragma unroll
            for (int f = 0; f < 8; ++f) vbB[f] = *(const bf16x8*)(vt + f * 512);
        }

        SUBTILE(cur, 1, it, vbB)

        __syncthreads();   // next 2 tiles staged + all waves done with buf[cur]
    }
#undef SUBTILE

    // ---- write partials ----
    if (lane < 32) {
        Mp[ks * S_LEN + qrow] = m_run;
        Lp[ks * S_LEN + qrow] = l_run;
    }
    half_t* pb = P16 + (size_t)(ks * 256 + qsub) * (128 * 32);
    #pragma unroll
    for (int d = 0; d < 4; ++d)
        #pragma unroll
        for (int reg = 0; reg < 16; ++reg) {
            int drow = d * 32 + (reg & 3) + 8 * (reg >> 2) + 4 * hi;
            pb[drow * 32 + l5] = (half_t)oacc[d][reg];
        }
}

// ---------------------------------------------------------------------------
// Phase B: merge 8 kv-split partials per q-row (m in exp2 domain).
// ---------------------------------------------------------------------------
__global__ __launch_bounds__(256) void attn_merge_23450521436217(
    const half_t* __restrict__ P16,
    const float*  __restrict__ Mp,
    const float*  __restrict__ Lp,
    float* __restrict__ O)
{
    const int tid  = threadIdx.x;
    const int qsub = blockIdx.x;

    __shared__ float W[8][32];
    __shared__ float Li[32];
    __shared__ float Ot[128][33];

    if (tid < 32) {
        const int qrow = qsub * 32 + tid;
        float m[8], l[8];
        #pragma unroll
        for (int ks = 0; ks < 8; ++ks) {
            m[ks] = Mp[ks * S_LEN + qrow];
            l[ks] = Lp[ks * S_LEN + qrow];
        }
        float M = m[0];
        #pragma unroll
        for (int ks = 1; ks < 8; ++ks) M = fmaxf(M, m[ks]);
        float L = 0.0f;
        #pragma unroll
        for (int ks = 0; ks < 8; ++ks) {
            float w = exp2f(m[ks] - M);
            W[ks][tid] = w;
            L += l[ks] * w;
        }
        Li[tid] = 1.0f / L;
    }
    __syncthreads();

    const int q  = tid & 31;
    const int dg = tid >> 5;          // 0..7
    #pragma unroll
    for (int j = 0; j < 16; ++j) {
        const int d = dg * 16 + j;
        float acc = 0.0f;
        #pragma unroll
        for (int ks = 0; ks < 8; ++ks)
            acc += W[ks][q] *
                   (float)P16[(size_t)(ks * 256 + qsub) * (128 * 32) + d * 32 + q];
        Ot[d][q] = acc;
    }
    __syncthreads();

    const int qq = tid >> 3;
    const int dv = (tid & 7) * 16;
    const float il = Li[qq];
    float* op = O + (size_t)(qsub * 32 + qq) * D_KK + dv;
    #pragma unroll
    for (int i = 0; i < 4; ++i) {
        float4 o;
        o.x = Ot[dv + i*4 + 0][qq] * il;
        o.y = Ot[dv + i*4 + 1][qq] * il;
        o.z = Ot[dv + i*4 + 2][qq] * il;
        o.w = Ot[dv + i*4 + 3][qq] * il;
        ((float4*)op)[i] = o;
    }
}

extern "C" void kernel_launch(void* const* d_in, const int* in_sizes, int n_in,
                              void* d_out, int out_size, void* d_ws, size_t ws_size,
                              hipStream_t stream) {
    const float* Q = (const float*)d_in[0];
    const float* K = (const float*)d_in[1];
    const float* V = (const float*)d_in[2];
    float* O = (float*)d_out;

    char* ws = (char*)d_ws;
    const size_t kf_b = (size_t)S_LEN * D_KK * 2;        // 2 MB
    __bf16* Kf = (__bf16*)(ws);
    __bf16* Vf = (__bf16*)(ws + kf_b);
    float*  Mp = (float*) (ws + 2 * kf_b);               // 256 KB
    float*  Lp = (float*) (ws + 2 * kf_b + 8 * S_LEN * 4);
    half_t* P16= (half_t*)(ws + 2 * kf_b + 16 * S_LEN * 4);  // 16.8 MB

    hipLaunchKernelGGL(prep_kv_23450521436217, dim3(S_LEN/32), dim3(256), 0, stream,
                       K, V, Kf, Vf);
    hipLaunchKernelGGL(attn_part_23450521436217, dim3(256), dim3(512), 0, stream,
                       Q, Kf, Vf, P16, Mp, Lp);
    hipLaunchKernelGGL(attn_merge_23450521436217, dim3(S_LEN/32), dim3(256), 0, stream,
                       P16, Mp, Lp, O);
}